// Round 5
// baseline (211.131 us; speedup 1.0000x reference)
//
#include <hip/hip_runtime.h>

#define PP 10
#define LL 6
#define NIMG 4
#define HW (1024*1024)
#define BINS 66          // 60 inter bins (l*10+p) + 6 count bins
#define NB 60
#define BX 256           // blocks per image
#define TPB 256
#define ITERS 4          // HW/4 / (BX*TPB) = 4, exact

// ws: partial[img][bx][b] = ws[(img*BX+bx)*BINS + b], non-atomic stores.

__global__ __launch_bounds__(TPB, 3) void accum_kernel(
    const float* __restrict__ pred,
    const int*   __restrict__ pconn,
    const int*   __restrict__ lconn,
    float*       __restrict__ ws)
{
    // Reduction staging only (not in hot loop): ld[bin*64 + unit],
    // unit = wave*16 + (lane>>2). 16.9 KB.
    __shared__ float ld[BINS * 64];

    const int tid = threadIdx.x;
    const int img = blockIdx.y;
    const size_t base = (size_t)img * HW;

    const float4* __restrict__ p4  = (const float4*)(pred  + base);
    const int4*   __restrict__ pc4 = (const int4*)(pconn + base);
    const int4*   __restrict__ lc4 = (const int4*)(lconn + base);

    const int v0 = blockIdx.x * TPB + tid;
    const int stride = BX * TPB;   // 65536 vec4s

    // Hoist all 12 loads (48 VGPRs) -> single latency wait, max overlap.
    float4 p[ITERS]; int4 pc[ITERS], lc[ITERS];
#pragma unroll
    for (int i = 0; i < ITERS; ++i) {
        const int v = v0 + i * stride;
        p[i]  = p4[v];
        pc[i] = pc4[v];
        lc[i] = lc4[v];
    }

    // All-register accumulators: no LDS RMW chains, no DS latency.
    float acc[LL][PP];
    float cnt[LL];
#pragma unroll
    for (int l = 0; l < LL; ++l) {
        cnt[l] = 0.0f;
#pragma unroll
        for (int q = 0; q < PP; ++q) acc[l][q] = 0.0f;
    }

#pragma unroll
    for (int i = 0; i < ITERS; ++i) {
#pragma unroll
        for (int c = 0; c < 4; ++c) {
            const float pv  = (c == 0) ? p[i].x  : (c == 1) ? p[i].y  : (c == 2) ? p[i].z  : p[i].w;
            const int   lcv = (c == 0) ? lc[i].x : (c == 1) ? lc[i].y : (c == 2) ? lc[i].z : lc[i].w;
            const int   pcv = (c == 0) ? pc[i].x : (c == 1) ? pc[i].y : (c == 2) ? pc[i].z : pc[i].w;
            float op[PP];
#pragma unroll
            for (int q = 0; q < PP; ++q) op[q] = (pcv == q) ? 1.0f : 0.0f;
#pragma unroll
            for (int l = 0; l < LL; ++l) {
                const float ol = (lcv == l) ? 1.0f : 0.0f;
                cnt[l] += ol;
                const float hl = pv * ol;
#pragma unroll
                for (int q = 0; q < PP; ++q)
                    acc[l][q] = fmaf(hl, op[q], acc[l][q]);
            }
        }
    }

    // 2-step shuffle reduce (quad sums), then LDS transpose.
    const int unit = (tid >> 6) * 16 + ((tid & 63) >> 2);  // 0..63
    const bool writer = ((tid & 3) == 0);
#pragma unroll
    for (int l = 0; l < LL; ++l) {
#pragma unroll
        for (int q = 0; q < PP; ++q) {
            float s = acc[l][q];
            s += __shfl_down(s, 1, 64);
            s += __shfl_down(s, 2, 64);
            if (writer) ld[(l * PP + q) * 64 + unit] = s;
        }
        float s = cnt[l];
        s += __shfl_down(s, 1, 64);
        s += __shfl_down(s, 2, 64);
        if (writer) ld[(NB + l) * 64 + unit] = s;
    }
    __syncthreads();

    // Threads 0..65: sum 64 contiguous floats (16 float4 reads), store partial.
    if (tid < BINS) {
        const float4* row = (const float4*)(ld + tid * 64);
        float s = 0.0f;
#pragma unroll
        for (int i = 0; i < 16; ++i) {
            const float4 t4 = row[i];
            s += t4.x + t4.y + t4.z + t4.w;
        }
        ws[((size_t)img * BX + blockIdx.x) * BINS + tid] = s;
    }
}

__global__ __launch_bounds__(1024) void finalize_kernel(
    const float* __restrict__ ws, float* __restrict__ out)
{
    __shared__ float part[4][NIMG * BINS];   // [sub][img*66+b]
    __shared__ float red[NIMG * BINS];
    __shared__ float contrib[NIMG];
    const int t = threadIdx.x;

    // 1056 tasks: (img,bin) x 4 sub-chunks of 64 bx each.
    for (int T = t; T < 4 * NIMG * BINS; T += 1024) {
        const int ib = T >> 2, sub = T & 3;
        const int img = ib / BINS, b = ib % BINS;
        const float* basep = ws + ((size_t)img * BX + sub) * BINS + b;
        float s = 0.0f;
#pragma unroll 8
        for (int j = 0; j < BX / 4; ++j) s += basep[(size_t)j * 4 * BINS];
        part[sub][ib] = s;
    }
    __syncthreads();

    if (t < NIMG * BINS)
        red[t] = part[0][t] + part[1][t] + part[2][t] + part[3][t];
    __syncthreads();

    if (t < NIMG) {
        const float* b = red + t * BINS;
        float inter[LL][PP], pred_area[PP], label_area[LL];
        for (int p = 0; p < PP; ++p) pred_area[p] = 0.0f;
        for (int l = 0; l < LL; ++l) {
            label_area[l] = b[NB + l];
            for (int p = 0; p < PP; ++p) {
                inter[l][p] = b[l * PP + p];
                pred_area[p] += inter[l][p];
            }
        }
        float ious[LL][PP];
        for (int l = 1; l < LL; ++l) {
            for (int p = 1; p < PP; ++p) {
                float in = inter[l][p];
                float un = label_area[l] + pred_area[p] - in;
                float iou;
                if (in == 0.0f)      iou = 0.0f;
                else if (un == 0.0f) iou = 1.0f;
                else                 iou = in / un;
                ious[l][p] = iou;
            }
        }
        float pair_conn_sum = 0.0f;
        for (int l = 1; l < LL; ++l) {
            float pc = 0.0f; int pn = 0;
            for (int p = 1; p < PP; ++p) {
                pc += ious[l][p];
                pn += (ious[l][p] != 0.0f) ? 1 : 0;
            }
            if (pn > 0) pair_conn_sum += pc / (float)pn;
        }
        int lone = 0;
        for (int p = 1; p < PP; ++p) {
            float cs = 0.0f;
            for (int l = 1; l < LL; ++l) cs += ious[l][p];
            lone += (cs == 0.0f) ? 1 : 0;
        }
        contrib[t] = 1.0f - pair_conn_sum / (5.0f + (float)lone);
    }
    __syncthreads();
    if (t == 0)
        out[0] = (contrib[0] + contrib[1] + contrib[2] + contrib[3]) * 0.25f;
}

extern "C" void kernel_launch(void* const* d_in, const int* in_sizes, int n_in,
                              void* d_out, int out_size, void* d_ws, size_t ws_size,
                              hipStream_t stream) {
    const float* pred  = (const float*)d_in[0];
    const int*   pconn = (const int*)d_in[1];
    const int*   lconn = (const int*)d_in[2];
    float* out = (float*)d_out;
    float* ws  = (float*)d_ws;

    dim3 grid(BX, NIMG);
    accum_kernel<<<grid, TPB, 0, stream>>>(pred, pconn, lconn, ws);

    finalize_kernel<<<1, 1024, 0, stream>>>(ws, out);
}

// Round 6
// 112.466 us; speedup vs baseline: 1.8773x; 1.8773x over previous
//
#include <hip/hip_runtime.h>

#define PP 10
#define LL 6
#define NIMG 4
#define HW (1024*1024)
#define NBO 59    // 45 inter(l=1..5,p=1..9) + 9 pred_area(p=1..9) + 5 cnt(l=1..5)
#define BINS 60   // padded stride in ws
#define BX 256    // blocks per image
#define TPB 256
#define ITERS 4   // HW/4 / (BX*TPB) = 4, exact

// ws: partial[img][bx][b] = ws[(img*BX+bx)*BINS + b], non-atomic stores.

__global__ __launch_bounds__(TPB) void accum_kernel(
    const float* __restrict__ pred,
    const int*   __restrict__ pconn,
    const int*   __restrict__ lconn,
    float*       __restrict__ ws)
{
    __shared__ float ld[NBO * 64];   // reduction staging only, 15.1 KB

    const int tid = threadIdx.x;
    const int img = blockIdx.y;
    const size_t base = (size_t)img * HW;

    const float4* __restrict__ p4  = (const float4*)(pred  + base);
    const int4*   __restrict__ pc4 = (const int4*)(pconn + base);
    const int4*   __restrict__ lc4 = (const int4*)(lconn + base);

    const int v0 = blockIdx.x * TPB + tid;
    const int stride = BX * TPB;   // 65536 vec4s

    // 59 register accumulators (trimmed from 66 — R5 spilled at 66+48 live).
    float A[45];    // inter[l=1..5][p=1..9]: A[(l-1)*9 + (p-1)]
    float PA[9];    // pred_area[p=1..9] over ALL l
    float CNT[5];   // label_area[l=1..5]
#pragma unroll
    for (int i = 0; i < 45; ++i) A[i] = 0.0f;
#pragma unroll
    for (int i = 0; i < 9; ++i) PA[i] = 0.0f;
#pragma unroll
    for (int i = 0; i < 5; ++i) CNT[i] = 0.0f;

    // One-ahead software pipeline: only 2 vec4-triples (24 regs) live, not 12.
    float4 pcur = p4[v0];
    int4   pccur = pc4[v0];
    int4   lccur = lc4[v0];

#pragma unroll
    for (int i = 0; i < ITERS; ++i) {
        float4 pnxt; int4 pcnxt, lcnxt;
        if (i + 1 < ITERS) {
            const int v = v0 + (i + 1) * stride;
            pnxt  = p4[v];
            pcnxt = pc4[v];
            lcnxt = lc4[v];
        }
#pragma unroll
        for (int c = 0; c < 4; ++c) {
            const float pv  = (c == 0) ? pcur.x  : (c == 1) ? pcur.y  : (c == 2) ? pcur.z  : pcur.w;
            const int   lcv = (c == 0) ? lccur.x : (c == 1) ? lccur.y : (c == 2) ? lccur.z : lccur.w;
            const int   pcv = (c == 0) ? pccur.x : (c == 1) ? pccur.y : (c == 2) ? pccur.z : pccur.w;

            float op[PP];  // one-hot for p=1..9 only
#pragma unroll
            for (int q = 1; q < PP; ++q) op[q] = (pcv == q) ? 1.0f : 0.0f;
            // pred_area over all l: direct FMA with pv
#pragma unroll
            for (int q = 1; q < PP; ++q) PA[q - 1] = fmaf(pv, op[q], PA[q - 1]);
#pragma unroll
            for (int l = 1; l < LL; ++l) {
                const bool ol = (lcv == l);
                CNT[l - 1] += ol ? 1.0f : 0.0f;
                const float hl = ol ? pv : 0.0f;
#pragma unroll
                for (int q = 1; q < PP; ++q)
                    A[(l - 1) * 9 + (q - 1)] = fmaf(hl, op[q], A[(l - 1) * 9 + (q - 1)]);
            }
        }
        pcur = pnxt; pccur = pcnxt; lccur = lcnxt;
    }

    // Quad shuffle-reduce (4->1), stage into ld[bin*64 + unit].
    const int unit = (tid >> 6) * 16 + ((tid & 63) >> 2);  // 0..63
    const bool writer = ((tid & 3) == 0);
#pragma unroll
    for (int b = 0; b < 45; ++b) {
        float s = A[b];
        s += __shfl_down(s, 1, 64); s += __shfl_down(s, 2, 64);
        if (writer) ld[b * 64 + unit] = s;
    }
#pragma unroll
    for (int b = 0; b < 9; ++b) {
        float s = PA[b];
        s += __shfl_down(s, 1, 64); s += __shfl_down(s, 2, 64);
        if (writer) ld[(45 + b) * 64 + unit] = s;
    }
#pragma unroll
    for (int b = 0; b < 5; ++b) {
        float s = CNT[b];
        s += __shfl_down(s, 1, 64); s += __shfl_down(s, 2, 64);
        if (writer) ld[(54 + b) * 64 + unit] = s;
    }
    __syncthreads();

    // Threads 0..58: sum own row of 64 (rotated float4 reads -> no conflicts).
    if (tid < NBO) {
        const float4* row = (const float4*)(ld + tid * 64);
        float s = 0.0f;
#pragma unroll
        for (int i = 0; i < 16; ++i) {
            const float4 t4 = row[(i + tid) & 15];
            s += t4.x + t4.y + t4.z + t4.w;
        }
        ws[((size_t)img * BX + blockIdx.x) * BINS + tid] = s;
    }
}

__global__ __launch_bounds__(1024) void finalize_kernel(
    const float* __restrict__ ws, float* __restrict__ out)
{
    __shared__ float part[4][NIMG * BINS];
    __shared__ float red[NIMG * BINS];
    __shared__ float contrib[NIMG];
    const int t = threadIdx.x;

    // 960 tasks: (img,bin) x 4 sub-chunks of 64 bx each.
    for (int T = t; T < 4 * NIMG * BINS; T += 1024) {
        const int ib = T >> 2, sub = T & 3;
        const int img = ib / BINS, b = ib % BINS;
        float s = 0.0f;
        if (b < NBO) {
            const float* basep = ws + ((size_t)img * BX + sub) * BINS + b;
#pragma unroll 8
            for (int j = 0; j < BX / 4; ++j) s += basep[(size_t)j * 4 * BINS];
        }
        part[sub][ib] = s;
    }
    __syncthreads();

    if (t < NIMG * BINS)
        red[t] = part[0][t] + part[1][t] + part[2][t] + part[3][t];
    __syncthreads();

    if (t < NIMG) {
        const float* b = red + t * BINS;
        // b[0..44]=inter(l-1,p-1), b[45..53]=pred_area(p-1), b[54..58]=label_area(l-1)
        float colsum[9];
#pragma unroll
        for (int p = 0; p < 9; ++p) colsum[p] = 0.0f;
        float pair_conn_sum = 0.0f;
        for (int l = 0; l < 5; ++l) {
            const float la = b[54 + l];
            float pc = 0.0f; int pn = 0;
            for (int p = 0; p < 9; ++p) {
                const float in = b[l * 9 + p];
                const float un = la + b[45 + p] - in;
                float iou;
                if (in == 0.0f)      iou = 0.0f;
                else if (un == 0.0f) iou = 1.0f;
                else                 iou = in / un;
                colsum[p] += iou;
                pc += iou;
                pn += (iou != 0.0f) ? 1 : 0;
            }
            if (pn > 0) pair_conn_sum += pc / (float)pn;
        }
        int lone = 0;
        for (int p = 0; p < 9; ++p) lone += (colsum[p] == 0.0f) ? 1 : 0;
        contrib[t] = 1.0f - pair_conn_sum / (5.0f + (float)lone);
    }
    __syncthreads();
    if (t == 0)
        out[0] = (contrib[0] + contrib[1] + contrib[2] + contrib[3]) * 0.25f;
}

extern "C" void kernel_launch(void* const* d_in, const int* in_sizes, int n_in,
                              void* d_out, int out_size, void* d_ws, size_t ws_size,
                              hipStream_t stream) {
    const float* pred  = (const float*)d_in[0];
    const int*   pconn = (const int*)d_in[1];
    const int*   lconn = (const int*)d_in[2];
    float* out = (float*)d_out;
    float* ws  = (float*)d_ws;

    dim3 grid(BX, NIMG);
    accum_kernel<<<grid, TPB, 0, stream>>>(pred, pconn, lconn, ws);

    finalize_kernel<<<1, 1024, 0, stream>>>(ws, out);
}